// Round 7
// baseline (565.589 us; speedup 1.0000x reference)
//
#include <hip/hip_runtime.h>
#include <hip/hip_bf16.h>

#define NN 524288     // nodes
#define NE 2097152    // edges
#define NS 8192       // subgraphs
#define NG 64         // groups
#define FIN 64
#define HIDDEN 128

#define NB 512        // coarse bins (dst >> 10)
#define BIN_NODES 1024
#define CAP 4608      // bin capacity: mean 4096 + 8 sigma

typedef __attribute__((ext_vector_type(8))) unsigned short ushort8;
typedef __attribute__((ext_vector_type(8))) short bf16x8;
typedef __attribute__((ext_vector_type(4))) float floatx4;

__device__ __forceinline__ unsigned short f2b(float f) {
  union { float f; unsigned int u; } c; c.f = f;
  unsigned int u = c.u;
  unsigned int r = (u + 0x7FFFu + ((u >> 16) & 1u)) >> 16;  // RNE
  return (unsigned short)r;
}
__device__ __forceinline__ float b2f(unsigned short b) {
  union { unsigned int u; float f; } c; c.u = ((unsigned int)b) << 16;
  return c.f;
}

// ---------------------------------------------------------------------------
// K0a: cast x -> bf16 (xb).  8 floats per thread.
// ---------------------------------------------------------------------------
__global__ __launch_bounds__(256) void k_cast(const float* __restrict__ x,
                                              unsigned short* __restrict__ xb) {
  size_t i = ((size_t)blockIdx.x * 256 + threadIdx.x) * 8;
  float4 v0 = *(const float4*)(x + i);
  float4 v1 = *(const float4*)(x + i + 4);
  ushort8 r;
  r[0] = f2b(v0.x); r[1] = f2b(v0.y); r[2] = f2b(v0.z); r[3] = f2b(v0.w);
  r[4] = f2b(v1.x); r[5] = f2b(v1.y); r[6] = f2b(v1.z); r[7] = f2b(v1.w);
  *(ushort8*)(xb + i) = r;
}

// K0b: build Wt[n][k] = bf16( k<64 ? Wl[k][n] : Wr[k-64][n] ), 128x128
__global__ __launch_bounds__(256) void k_prepw(const float* __restrict__ Wl,
                                               const float* __restrict__ Wr,
                                               unsigned short* __restrict__ Wt) {
  int i = blockIdx.x * 256 + threadIdx.x;  // 64 blocks -> 16384
  int n = i >> 7, k = i & 127;
  float v = (k < FIN) ? Wl[k * HIDDEN + n] : Wr[(k - FIN) * HIDDEN + n];
  Wt[n * HIDDEN + k] = f2b(v);
}

// ---------------------------------------------------------------------------
// K1a: coarse binning.  Each block: 4096 edges, LDS hist over 512 bins,
// one chunk-reservation atomic per (block,bin), packed write into bin region.
// pack = (dst_local << 19) | src   (src < 2^19, dst_local < 2^10)
// ---------------------------------------------------------------------------
__global__ __launch_bounds__(256) void k_bin1(const int* __restrict__ ei,
                                              int* __restrict__ binCursor,
                                              unsigned int* __restrict__ pairs) {
  __shared__ unsigned int pk[4096];
  __shared__ unsigned short bn[4096];
  __shared__ int cnt[NB];
  __shared__ int base[NB];
  const int t = threadIdx.x;
  const int eBase = blockIdx.x * 4096;
  cnt[t] = 0; cnt[t + 256] = 0;
  __syncthreads();
#pragma unroll
  for (int i = 0; i < 16; ++i) {
    int j = i * 256 + t;
    int e = eBase + j;
    int src = ei[e];
    int dst = ei[NE + e];
    int bin = dst >> 10;
    pk[j] = ((unsigned int)(dst & 1023) << 19) | (unsigned int)src;
    bn[j] = (unsigned short)bin;
    atomicAdd(&cnt[bin], 1);
  }
  __syncthreads();
  {
    int c0 = cnt[t], c1 = cnt[t + 256];
    base[t]       = atomicAdd(&binCursor[t], c0);
    base[t + 256] = atomicAdd(&binCursor[t + 256], c1);
    cnt[t] = 0; cnt[t + 256] = 0;
  }
  __syncthreads();
#pragma unroll
  for (int i = 0; i < 16; ++i) {
    int j = i * 256 + t;
    int bin = bn[j];
    int ofs = atomicAdd(&cnt[bin], 1);
    pairs[(size_t)bin * CAP + base[bin] + ofs] = pk[j];
  }
}

// ---------------------------------------------------------------------------
// K1b: per-bin local CSR.  One block per bin: stage pairs to LDS, LDS hist of
// 1024 local nodes, LDS scan -> start offsets S[n + (n>>10)] (+sentinel),
// then place src in-place over the bin's pairs region via LDS cursors.
// ---------------------------------------------------------------------------
__global__ __launch_bounds__(256) void k_bin2(const int* __restrict__ binCursor,
                                              unsigned int* __restrict__ pairs,
                                              int* __restrict__ S) {
  __shared__ unsigned int pk[CAP];
  __shared__ int cnt[BIN_NODES];
  __shared__ int ps[256];
  const int t = threadIdx.x;
  const int b = blockIdx.x;
  int total = binCursor[b];
  if (total > CAP) total = CAP;   // statistical impossibility; guard LDS
  const int gbase = b * CAP;

  for (int i = t; i < total; i += 256) pk[i] = pairs[gbase + i];
  cnt[t] = 0; cnt[t + 256] = 0; cnt[t + 512] = 0; cnt[t + 768] = 0;
  __syncthreads();

  for (int i = t; i < total; i += 256) atomicAdd(&cnt[pk[i] >> 19], 1);
  __syncthreads();

  // scan: thread t owns local nodes 4t..4t+3
  int c0 = cnt[4 * t], c1 = cnt[4 * t + 1], c2 = cnt[4 * t + 2], c3 = cnt[4 * t + 3];
  int tot4 = c0 + c1 + c2 + c3;
  ps[t] = tot4;
  __syncthreads();
  for (int off = 1; off < 256; off <<= 1) {
    int v = 0;
    if (t >= off) v = ps[t - off];
    __syncthreads();
    ps[t] += v;
    __syncthreads();
  }
  int e0 = ps[t] - tot4;
  int e1 = e0 + c0, e2 = e1 + c1, e3 = e2 + c2;
  cnt[4 * t] = e0; cnt[4 * t + 1] = e1; cnt[4 * t + 2] = e2; cnt[4 * t + 3] = e3;
  int sidx = b * (BIN_NODES + 1) + 4 * t;
  S[sidx]     = gbase + e0;
  S[sidx + 1] = gbase + e1;
  S[sidx + 2] = gbase + e2;
  S[sidx + 3] = gbase + e3;
  if (t == 0) S[b * (BIN_NODES + 1) + BIN_NODES] = gbase + total;
  __syncthreads();

  for (int i = t; i < total; i += 256) {
    unsigned int p = pk[i];
    int dl = p >> 19;
    int ofs = atomicAdd(&cnt[dl], 1);
    pairs[gbase + ofs] = p & 0x7FFFFu;   // now holds src only
  }
}

// ---------------------------------------------------------------------------
// K2 fused: aggregate + MFMA conv + pool.  Per block 128 nodes.
//  phase 0: B fragments -> registers (L1-hot Wt; latency hides under phase 1)
//  phase 1: per-node mean-aggregate via 8-lane groups, bf16 rows -> LDS A
//           A[r] = [ mean_agg(r) | xb(r) ]   (K=128)
//  phase 2: MFMA 128x128x128, B from regs, A from LDS
//  phase 3: bias+relu -> h (bf16) in LDS; segmented pool -> g atomics
// ---------------------------------------------------------------------------
#define CB_NODES 128
__global__ __launch_bounds__(256, 2) void k_agconv(const unsigned short* __restrict__ xb,
                                                   const int* __restrict__ S,
                                                   const unsigned int* __restrict__ bucket,
                                                   const int* __restrict__ node_batch,
                                                   const unsigned short* __restrict__ Wt,
                                                   const float* __restrict__ bconv,
                                                   float* __restrict__ g) {
  __shared__ unsigned short As[128 * 136];  // A[m][k]; later reused as h[m][n]
  __shared__ int nb_s[CB_NODES];
  const int t = threadIdx.x;
  const int n0 = blockIdx.x * CB_NODES;
  const int lane = t & 63;
  const int l16 = lane & 15;
  const int quad = lane >> 4;

  // phase 0: B fragments (shared across waves; indexed by lane only)
  bf16x8 Breg[8][4];
#pragma unroll
  for (int nt = 0; nt < 8; ++nt)
#pragma unroll
    for (int ks = 0; ks < 4; ++ks)
      Breg[nt][ks] = *(const bf16x8*)(Wt + (size_t)(nt * 16 + l16) * HIDDEN + ks * 32 + quad * 8);

  if (t < CB_NODES) nb_s[t] = node_batch[n0 + t];

  // phase 1: aggregation.  8-lane group per node, 32 groups, 4 iterations.
  const int g8 = t >> 3;
  const int l8 = t & 7;
#pragma unroll
  for (int it = 0; it < 4; ++it) {
    int r = it * 32 + g8;          // local row
    int n = n0 + r;
    int sidx = n + (n >> 10);
    int rp0 = S[sidx];
    int rp1 = S[sidx + 1];

    float a0[8] = {0,0,0,0,0,0,0,0};
    float a1[8] = {0,0,0,0,0,0,0,0};
    float a2[8] = {0,0,0,0,0,0,0,0};
    float a3[8] = {0,0,0,0,0,0,0,0};
    int e = rp0;
    for (; e + 3 < rp1; e += 4) {
      int s0 = bucket[e], s1 = bucket[e + 1], s2 = bucket[e + 2], s3 = bucket[e + 3];
      ushort8 v0 = *(const ushort8*)(xb + (size_t)s0 * FIN + (l8 << 3));
      ushort8 v1 = *(const ushort8*)(xb + (size_t)s1 * FIN + (l8 << 3));
      ushort8 v2 = *(const ushort8*)(xb + (size_t)s2 * FIN + (l8 << 3));
      ushort8 v3 = *(const ushort8*)(xb + (size_t)s3 * FIN + (l8 << 3));
#pragma unroll
      for (int j = 0; j < 8; ++j) {
        a0[j] += b2f(v0[j]); a1[j] += b2f(v1[j]);
        a2[j] += b2f(v2[j]); a3[j] += b2f(v3[j]);
      }
    }
    for (; e < rp1; ++e) {
      int s0 = bucket[e];
      ushort8 v0 = *(const ushort8*)(xb + (size_t)s0 * FIN + (l8 << 3));
#pragma unroll
      for (int j = 0; j < 8; ++j) a0[j] += b2f(v0[j]);
    }
    float rdeg = 1.f / fmaxf((float)(rp1 - rp0), 1.f);
    ushort8 m;
#pragma unroll
    for (int j = 0; j < 8; ++j)
      m[j] = f2b((a0[j] + a1[j] + a2[j] + a3[j]) * rdeg);
    *(ushort8*)(As + r * 136 + l8 * 8) = m;
    *(ushort8*)(As + r * 136 + 64 + l8 * 8) =
        *(const ushort8*)(xb + (size_t)n * FIN + l8 * 8);
  }
  __syncthreads();

  // phase 2: MFMA
  const int wave = t >> 6;     // rows wave*32 .. +31

  floatx4 acc[2][8];
#pragma unroll
  for (int mt = 0; mt < 2; ++mt)
#pragma unroll
    for (int nt = 0; nt < 8; ++nt) acc[mt][nt] = (floatx4){0.f, 0.f, 0.f, 0.f};

  float bv[8];
#pragma unroll
  for (int nt = 0; nt < 8; ++nt) bv[nt] = bconv[nt * 16 + l16];

#pragma unroll
  for (int ks = 0; ks < 4; ++ks) {
    bf16x8 a0 = *(const bf16x8*)(As + (wave * 32 + l16) * 136 + ks * 32 + quad * 8);
    bf16x8 a1 = *(const bf16x8*)(As + (wave * 32 + 16 + l16) * 136 + ks * 32 + quad * 8);
#pragma unroll
    for (int nt = 0; nt < 8; ++nt) {
      acc[0][nt] = __builtin_amdgcn_mfma_f32_16x16x32_bf16(a0, Breg[nt][ks], acc[0][nt], 0, 0, 0);
      acc[1][nt] = __builtin_amdgcn_mfma_f32_16x16x32_bf16(a1, Breg[nt][ks], acc[1][nt], 0, 0, 0);
    }
  }

  // phase 3: bias+relu -> h bf16 into As (each wave overwrites only its rows)
#pragma unroll
  for (int mt = 0; mt < 2; ++mt)
#pragma unroll
    for (int nt = 0; nt < 8; ++nt) {
      int col = nt * 16 + l16;
#pragma unroll
      for (int r = 0; r < 4; ++r) {
        int row = wave * 32 + mt * 16 + quad * 4 + r;
        float hv = fmaxf(acc[mt][nt][r] + bv[nt], 0.f);
        As[row * 136 + col] = f2b(hv);
      }
    }
  __syncthreads();

  // segmented pool: 2 threads per col, 64 nodes each (sorted node_batch)
  {
    int j = t & 127;
    int half = t >> 7;
    int ns = half * 64, ne = ns + 64;
    float sum = 0.f;
    int cur = nb_s[ns];
    for (int n = ns; n < ne; ++n) {
      int b = nb_s[n];
      if (b != cur) {
        unsafeAtomicAdd(&g[(size_t)cur * HIDDEN + j], sum);
        sum = 0.f;
        cur = b;
      }
      sum += b2f(As[n * 136 + j]);
    }
    unsafeAtomicAdd(&g[(size_t)cur * HIDDEN + j], sum);
  }
}

// ---------------------------------------------------------------------------
// K3: MLP head, one wave per subgraph.
// ---------------------------------------------------------------------------
__global__ __launch_bounds__(256) void k_head(const float* __restrict__ g,
                                              const float* __restrict__ W1,
                                              const float* __restrict__ b1,
                                              const float* __restrict__ W2,
                                              const float* __restrict__ b2,
                                              const float* __restrict__ wts,
                                              const int* __restrict__ sgb,
                                              float* __restrict__ egy,
                                              float* __restrict__ nrm) {
  int s = blockIdx.x * 4 + (threadIdx.x >> 6);
  int lane = threadIdx.x & 63;
  const float* grow = g + (size_t)s * HIDDEN;
  float acc0 = b1[lane];
  float acc1 = b1[lane + 64];
  for (int k = 0; k < HIDDEN; ++k) {
    float gk = grow[k];  // wave-uniform
    acc0 = fmaf(gk, W1[k * HIDDEN + lane], acc0);
    acc1 = fmaf(gk, W1[k * HIDDEN + 64 + lane], acc1);
  }
  float t0 = acc0 > 0.f ? acc0 : 0.01f * acc0;
  float t1 = acc1 > 0.f ? acc1 : 0.01f * acc1;
  float part = t0 * W2[lane] + t1 * W2[lane + 64];
#pragma unroll
  for (int off = 32; off > 0; off >>= 1) part += __shfl_down(part, off, 64);
  if (lane == 0) {
    float sval = part + b2[0];
    float w = wts[s];
    int grp = sgb[s];
    unsafeAtomicAdd(&egy[grp], sval * w);
    unsafeAtomicAdd(&nrm[grp], w);
  }
}

__global__ void k_final(const float* __restrict__ egy,
                        const float* __restrict__ nrm,
                        float* __restrict__ out) {
  int t = threadIdx.x;
  out[t] = egy[t] / nrm[t];
}

// ---------------------------------------------------------------------------
extern "C" void kernel_launch(void* const* d_in, const int* in_sizes, int n_in,
                              void* d_out, int out_size, void* d_ws, size_t ws_size,
                              hipStream_t stream) {
  const float* x   = (const float*)d_in[0];
  const int*   ei  = (const int*)d_in[1];
  const int*   nb  = (const int*)d_in[2];
  const float* wts = (const float*)d_in[3];
  const int*   sgb = (const int*)d_in[4];
  const float* Wl  = (const float*)d_in[5];
  const float* Wr  = (const float*)d_in[6];
  const float* bcv = (const float*)d_in[7];
  const float* W1  = (const float*)d_in[8];
  const float* b1  = (const float*)d_in[9];
  const float* W2  = (const float*)d_in[10];
  const float* b2  = (const float*)d_in[11];
  float* out = (float*)d_out;

  // ws layout (4B units), zeroed region first:
  //   binCursor[512] | g[NS*128] | egy[64] | nrm[64]   <- memset 0
  //   S[512*1025] | pairs[512*4608] | xb[NN*64 bf16] | Wt[16384 bf16]
  int*   binCursor = (int*)d_ws;
  float* g         = (float*)(binCursor + NB);
  float* egy       = g + (size_t)NS * HIDDEN;
  float* nrm       = egy + NG;
  int*   S         = (int*)(nrm + NG);
  unsigned int* pairs = (unsigned int*)(S + NB * (BIN_NODES + 1));
  unsigned short* xb   = (unsigned short*)(pairs + (size_t)NB * CAP);
  unsigned short* Wt   = xb + (size_t)NN * FIN;

  size_t zero_bytes = ((size_t)NB + (size_t)NS * HIDDEN + 2 * NG) * 4;
  hipMemsetAsync(d_ws, 0, zero_bytes, stream);

  k_cast <<<(NN * FIN) / (256 * 8), 256, 0, stream>>>(x, xb);
  k_prepw<<<64, 256, 0, stream>>>(Wl, Wr, Wt);
  k_bin1 <<<NE / 4096, 256, 0, stream>>>(ei, binCursor, pairs);
  k_bin2 <<<NB, 256, 0, stream>>>(binCursor, pairs, S);
  k_agconv<<<NN / CB_NODES, 256, 0, stream>>>(xb, S, pairs, nb, Wt, bcv, g);
  k_head<<<NS / 4, 256, 0, stream>>>(g, W1, b1, W2, b2, wts, sgb, egy, nrm);
  k_final<<<1, 64, 0, stream>>>(egy, nrm, out);
}